// Round 10
// baseline (302.797 us; speedup 1.0000x reference)
//
#include <hip/hip_runtime.h>

#define BN 2048   // batch
#define TN 2048   // time

__device__ __forceinline__ float ex2(float x){ return __builtin_amdgcn_exp2f(x); }
__device__ __forceinline__ float lg2(float x){ return __builtin_amdgcn_logf(x); }
__device__ __forceinline__ float rcpf(float x){ return __builtin_amdgcn_rcpf(x); }
// wave-uniform value -> SGPR (VALU allows 1 SGPR source per instruction)
__device__ __forceinline__ float rfl(float x){
    return __uint_as_float(__builtin_amdgcn_readfirstlane(__float_as_uint(x)));
}

constexpr float kLog2e = 1.4426950408889634f;
constexpr float kLn2   = 0.6931471805599453f;

__device__ __forceinline__ float fast_tanh(float x){
    float ax = fabsf(x);
    float e  = ex2(ax * (-2.0f * kLog2e));     // exp(-2|x|)
    float t  = (1.0f - e) * rcpf(1.0f + e);
    return copysignf(t, x);
}

__device__ __forceinline__ float sel4(float v0, float v1, float v2, float v3, int idx){
    float r = (idx == 1) ? v1 : v0;
    r = (idx == 2) ? v2 : r;
    r = (idx == 3) ? v3 : r;
    return r;
}

struct P1Params {
    float AL[4][4], M[4][4];      // SGPR-resident (rfl'd)
    float wsv[4], wwv[4], wnv[4]; // SGPR-resident
    float bwc, bnc;
    const float* sA; const float* sM;
};

// one generic CRF step, NCOL=4 (exp-space)
__device__ __forceinline__ void step4(
    const P1Params& pp, float fi0, float fi1, float fi2, float fi3,
    float bv, int tg, bool renorm,
    float (&P)[4][4], float (&lacc)[4], float& gold, int& prev)
{
    const bool hw = bv > 0.5f;
    const float bc = hw ? pp.bwc : pp.bnc;
    float g[4], gL[4];
    #pragma unroll
    for (int j = 0; j < 4; ++j) {
        float x = fmaf(bv, pp.wsv[j], bc);
        g[j]  = (hw ? pp.wwv[j] : pp.wnv[j]) * fast_tanh(x);
        gL[j] = g[j] * kLog2e;
    }
    const float fiL[4] = { fi0 * kLog2e, fi1 * kLog2e, fi2 * kLog2e, fi3 * kLog2e };
    float nP[4][4];
    #pragma unroll
    for (int i = 0; i < 4; ++i)
        #pragma unroll
        for (int j = 0; j < 4; ++j) nP[i][j] = 0.0f;
    #pragma unroll
    for (int k = 0; k < 4; ++k) {
        float Ek[4];
        #pragma unroll
        for (int i = 0; i < 4; ++i)
            Ek[i] = ex2(fmaf(gL[k], pp.M[i][k], fiL[i] + pp.AL[i][k]));
        #pragma unroll
        for (int j = 0; j < 4; ++j) {
            const float pk = P[k][j];
            #pragma unroll
            for (int i = 0; i < 4; ++i) nP[i][j] = fmaf(Ek[i], pk, nP[i][j]);
        }
    }
    #pragma unroll
    for (int i = 0; i < 4; ++i)
        #pragma unroll
        for (int j = 0; j < 4; ++j) P[i][j] = nP[i][j];

    const int idx = tg * 4 + prev;
    gold += pp.sA[idx] + sel4(g[0], g[1], g[2], g[3], prev) * pp.sM[idx]
          + sel4(fi0, fi1, fi2, fi3, tg);
    prev = tg;

    if (renorm) {     // exact pow2 renorm
        #pragma unroll
        for (int j = 0; j < 4; ++j) {
            float m = fmaxf(fmaxf(P[0][j], P[1][j]), fmaxf(P[2][j], P[3][j]));
            int ee = (int)((__float_as_uint(m) >> 23) & 255u) - 126;
            float sc = __uint_as_float((unsigned)(127 - ee) << 23);
            lacc[j] += (float)ee;
            #pragma unroll
            for (int i = 0; i < 4; ++i) P[i][j] *= sc;
        }
    }
}

// C = A∘B (A later, B earlier) in exp-space with per-column base-2 offsets.
__device__ __forceinline__ void compose4(
    const float (&Ae)[4][4], const float (&sa)[4],
    const float (&Be)[4][4], const float (&sb)[4],
    float (&Ce)[4][4], float (&sc)[4])
{
    const float maxA = fmaxf(fmaxf(sa[0], sa[1]), fmaxf(sa[2], sa[3]));
    float Ap[4][4];
    #pragma unroll
    for (int k = 0; k < 4; ++k) {
        const float wk = ex2(sa[k] - maxA);
        #pragma unroll
        for (int i = 0; i < 4; ++i) Ap[i][k] = Ae[i][k] * wk;
    }
    #pragma unroll
    for (int j = 0; j < 4; ++j) {
        float c0 = 0.f, c1 = 0.f, c2 = 0.f, c3 = 0.f;
        #pragma unroll
        for (int k = 0; k < 4; ++k) {
            const float bk = Be[k][j];
            c0 = fmaf(Ap[0][k], bk, c0);
            c1 = fmaf(Ap[1][k], bk, c1);
            c2 = fmaf(Ap[2][k], bk, c2);
            c3 = fmaf(Ap[3][k], bk, c3);
        }
        const float m = fmaxf(fmaxf(c0, c1), fmaxf(c2, c3));
        const int ee = (int)((__float_as_uint(m) >> 23) & 255u) - 126;
        const float scf = __uint_as_float((unsigned)(127 - ee) << 23);
        Ce[0][j] = c0 * scf; Ce[1][j] = c1 * scf;
        Ce[2][j] = c2 * scf; Ce[3][j] = c3 * scf;
        sc[j] = sb[j] + maxA + (float)ee;
    }
}

// ============ FUSED: 1 block = 1 batch; depth-2 pipeline, 64-VGPR target ============
// __launch_bounds__(256, 8): 8 waves/EU -> allocator capped at 64 VGPR, which
// doubles resident waves vs r8/r9's 68-VGPR (4 waves/EU band) — the diagnosed cap.
__global__ void __launch_bounds__(256, 8)
crf_fused(const float* __restrict__ feats, const float* __restrict__ bias,
          const int* __restrict__ tags, const float* __restrict__ trans,
          const float* __restrict__ wsh, const float* __restrict__ bno,
          const float* __restrict__ bwi, const float* __restrict__ wwo,
          const float* __restrict__ wno, const float* __restrict__ mult,
          float* __restrict__ out)
{
    const int w = threadIdx.x >> 6;     // wave 0..3
    const int L = threadIdx.x & 63;     // lane = local chunk
    const int b = blockIdx.x;
    const int c = threadIdx.x;          // global chunk id 0..255

    // 3200 floats = 12.8 KB: staging (4 waves x 192 float4 = 12288 B) overlaid
    // by the 128 x 25-float reduction slots (12800 B). 8 blocks/CU fits.
    __shared__ float shm[3200];
    __shared__ float sA[20], sM[16];    // sA[16..19] = trans[i*6+4] (init column)
    float4* stageW = ((float4*)shm) + w * 192;

    if (threadIdx.x < 16) {
        const int i = threadIdx.x >> 2, j = threadIdx.x & 3;
        sA[threadIdx.x] = trans[i * 6 + j];
        const float m0 = mult[j], m1 = mult[4 + j], m2 = mult[8 + j], m3 = mult[12 + j];
        const float mx = fmaxf(fmaxf(m0, m1), fmaxf(m2, m3));
        const float e0 = ex2((m0 - mx) * kLog2e), e1 = ex2((m1 - mx) * kLog2e);
        const float e2 = ex2((m2 - mx) * kLog2e), e3 = ex2((m3 - mx) * kLog2e);
        const float inv = rcpf(e0 + e1 + e2 + e3);
        const float ei = (i == 0) ? e0 : (i == 1) ? e1 : (i == 2) ? e2 : e3;
        sM[threadIdx.x] = (i == j) ? -1.0f : ei * inv;
        if (threadIdx.x < 4) sA[16 + threadIdx.x] = trans[threadIdx.x * 6 + 4];
    }
    __syncthreads();

    // wave-uniform constants -> SGPRs
    P1Params pp;
    #pragma unroll
    for (int i = 0; i < 4; ++i)
        #pragma unroll
        for (int j = 0; j < 4; ++j) {
            pp.AL[i][j] = rfl(trans[i * 6 + j] * kLog2e);
            pp.M[i][j]  = rfl(sM[i * 4 + j]);
        }
    #pragma unroll
    for (int j = 0; j < 4; ++j) {
        pp.wsv[j] = rfl(wsh[j]); pp.wwv[j] = rfl(wwo[j]); pp.wnv[j] = rfl(wno[j]);
    }
    pp.bwc = rfl(bwi[0]); pp.bnc = rfl(bno[0]);
    pp.sA = sA; pp.sM = sM;
    const float tcI0 = rfl(sA[16]), tcI1 = rfl(sA[17]);
    const float tcI2 = rfl(sA[18]), tcI3 = rfl(sA[19]);

    int prev = 0;
    if (c != 0) prev = tags[(size_t)b * TN + c * 8 - 1];

    // wave's feats window: 64 chunks x 12 float4; chunk cl owns [12*cl, 12*cl+12)
    const float4* gF = (const float4*)feats + (size_t)b * 3072 + (size_t)w * 768;
    const float* bbase = bias + (size_t)b * TN + c * 8;
    const int*   tbase = tags + (size_t)b * TN + c * 8;

    // per-lane staged-load base indices (stage s adds +3*s)
    int off[3];
    #pragma unroll
    for (int r = 0; r < 3; ++r) {
        const int S = r * 64 + L, cS = (S * 21846) >> 16;   // S/3, exact for S<192
        off[r] = cS * 12 + (S - cS * 3);
    }

    float P[4][4], lacc[4] = {0.f, 0.f, 0.f, 0.f};
    #pragma unroll
    for (int i = 0; i < 4; ++i)
        #pragma unroll
        for (int j = 0; j < 4; ++j) P[i][j] = (i == j) ? 1.0f : 0.0f;
    float gold = 0.0f;
    const bool isC0 = (c == 0);

    // ---- prologue: issue stages 0,1 (depth-2 pipeline; 24 staging VGPRs) ----
    float4 tF[2][3]; float2 bv2[2]; int2 tg2[2];
    #pragma unroll
    for (int s = 0; s < 2; ++s) {
        #pragma unroll
        for (int r = 0; r < 3; ++r) tF[s][r] = gF[off[r] + s * 3];
        bv2[s] = *(const float2*)(bbase + 2 * s);
        tg2[s] = *(const int2*)(tbase + 2 * s);
    }

    #pragma unroll
    for (int s = 0; s < 4; ++s) {
        const int sb = s & 1;
        // transpose stage s into wave-private LDS (vmcnt wait lands here)
        #pragma unroll
        for (int r = 0; r < 3; ++r) {
            const int S = r * 64 + L, cS = (S * 21846) >> 16, j = S - cS * 3;
            stageW[(j << 6) + ((cS + j) & 63)] = tF[sb][r];
        }
        const float bvx = bv2[sb].x, bvy = bv2[sb].y;
        const int   tgx = tg2[sb].x, tgy = tg2[sb].y;
        if (s < 2) {    // prefetch stage s+2 into the just-freed buffer
            #pragma unroll
            for (int r = 0; r < 3; ++r) tF[sb][r] = gF[off[r] + (s + 2) * 3];
            bv2[sb] = *(const float2*)(bbase + 2 * (s + 2));
            tg2[sb] = *(const int2*)(tbase + 2 * (s + 2));
        }
        const float4 fA = stageW[(0 << 6) + ( L      & 63)];
        const float4 fB = stageW[(1 << 6) + ((L + 1) & 63)];
        const float4 fC = stageW[(2 << 6) + ((L + 2) & 63)];
        {   // step 2s : floats 12s+0..3
            const float fi0 = fA.x, fi1 = fA.y, fi2 = fA.z, fi3 = fA.w;
            if (isC0 && s == 0) {
                const float a0 = fi0 + tcI0, a1 = fi1 + tcI1;
                const float a2 = fi2 + tcI2, a3 = fi3 + tcI3;
                const float mx = fmaxf(fmaxf(a0, a1), fmaxf(a2, a3));
                const float e0 = ex2((a0 - mx) * kLog2e);
                const float e1 = ex2((a1 - mx) * kLog2e);
                const float e2 = ex2((a2 - mx) * kLog2e);
                const float e3 = ex2((a3 - mx) * kLog2e);
                #pragma unroll
                for (int j = 0; j < 4; ++j) {
                    P[0][j] = e0; P[1][j] = e1; P[2][j] = e2; P[3][j] = e3;
                    lacc[j] = mx * kLog2e;
                }
                gold = sel4(tcI0, tcI1, tcI2, tcI3, tgx)
                     + sel4(fi0, fi1, fi2, fi3, tgx);
                prev = tgx;
            } else {
                step4(pp, fi0, fi1, fi2, fi3, bvx, tgx,
                      false, P, lacc, gold, prev);
            }
        }
        {   // step 2s+1 : floats 12s+6..9 ; renorm at steps 3 and 7 (s odd)
            const float fi0 = fB.z, fi1 = fB.w, fi2 = fC.x, fi3 = fC.y;
            step4(pp, fi0, fi1, fi2, fi3, bvy, tgy,
                  (s & 1) == 1, P, lacc, gold, prev);
        }
    }

    // ---- tree level 0 in registers via shuffle (same binary topology) ----
    {
        float oP[4][4], os[4];
        #pragma unroll
        for (int i = 0; i < 4; ++i)
            #pragma unroll
            for (int j = 0; j < 4; ++j) oP[i][j] = __shfl_xor(P[i][j], 1, 64);
        #pragma unroll
        for (int j = 0; j < 4; ++j) os[j] = __shfl_xor(lacc[j], 1, 64);
        const float og = __shfl_xor(gold, 1, 64);
        // even lane: own = earlier (chunk c), partner = later (chunk c+1)
        float Ce[4][4], sc[4];
        compose4(oP, os, P, lacc, Ce, sc);
        #pragma unroll
        for (int i = 0; i < 4; ++i)
            #pragma unroll
            for (int j = 0; j < 4; ++j) P[i][j] = Ce[i][j];
        #pragma unroll
        for (int j = 0; j < 4; ++j) lacc[j] = sc[j];
        gold += og;                     // meaningful on even lanes only
    }

    // ---- write 128 pair-results; then 7 LDS levels ----
    __syncthreads();                    // all staging reads done; safe to overlay
    if ((c & 1) == 0) {
        float* my = shm + (size_t)(c >> 1) * 25;
        #pragma unroll
        for (int i = 0; i < 4; ++i)
            #pragma unroll
            for (int j = 0; j < 4; ++j) my[i * 4 + j] = P[i][j];
        #pragma unroll
        for (int j = 0; j < 4; ++j) my[16 + j] = lacc[j];
        my[20] = gold;
    }
    #pragma unroll 1
    for (int l = 0; l < 7; ++l) {
        __syncthreads();
        const int cnt = 64 >> l;
        if (threadIdx.x < cnt) {
            float* se = shm + (size_t)(threadIdx.x << (l + 1)) * 25;  // earlier
            const float* sl = se + (25 << l);                         // later
            float Be_[4][4], sb[4], Ae[4][4], sa[4];
            #pragma unroll
            for (int i = 0; i < 4; ++i)
                #pragma unroll
                for (int j = 0; j < 4; ++j) { Be_[i][j] = se[i*4+j]; Ae[i][j] = sl[i*4+j]; }
            #pragma unroll
            for (int j = 0; j < 4; ++j) { sb[j] = se[16+j]; sa[j] = sl[16+j]; }
            const float gsum = se[20] + sl[20];
            float Ce[4][4], sc[4];
            compose4(Ae, sa, Be_, sb, Ce, sc);     // later ∘ earlier
            #pragma unroll
            for (int i = 0; i < 4; ++i)
                #pragma unroll
                for (int j = 0; j < 4; ++j) se[i*4+j] = Ce[i][j];
            #pragma unroll
            for (int j = 0; j < 4; ++j) se[16+j] = sc[j];
            se[20] = gsum;
        }
    }

    if (threadIdx.x == 0) {             // slot 0 was written by this thread
        const float p00 = shm[0], p10 = shm[4], p20 = shm[8], p30 = shm[12];
        const float so0 = shm[16];
        const float gall = shm[20];
        const float t50 = trans[30], t51 = trans[31], t52 = trans[32], t53 = trans[33];
        const float ssum = p00 * ex2(t50 * kLog2e) + p10 * ex2(t51 * kLog2e)
                         + p20 * ex2(t52 * kLog2e) + p30 * ex2(t53 * kLog2e);
        const float fwd = (so0 + lg2(ssum)) * kLn2;
        const int lastT = tags[(size_t)b * TN + TN - 1];
        const float gfin = gall + sel4(t50, t51, t52, t53, lastT);
        out[b] = fwd - gfin;
    }
}

extern "C" void kernel_launch(void* const* d_in, const int* in_sizes, int n_in,
                              void* d_out, int out_size, void* d_ws, size_t ws_size,
                              hipStream_t stream)
{
    const float* feats = (const float*)d_in[0];
    const float* bias  = (const float*)d_in[1];
    const int*   tags  = (const int*)d_in[2];
    const float* trans = (const float*)d_in[3];
    const float* wsh   = (const float*)d_in[4];
    const float* bno   = (const float*)d_in[5];
    const float* bwi   = (const float*)d_in[6];
    const float* wwo   = (const float*)d_in[7];
    const float* wno   = (const float*)d_in[8];
    const float* mult  = (const float*)d_in[9];
    float* out = (float*)d_out;
    (void)d_ws; (void)ws_size;   // workspace not needed

    crf_fused<<<BN, 256, 0, stream>>>(
        feats, bias, tags, trans, wsh, bno, bwi, wwo, wno, mult, out);
}

// Round 11
// 252.574 us; speedup vs baseline: 1.1988x; 1.1988x over previous
//
#include <hip/hip_runtime.h>

#define BN 2048   // batch
#define TN 2048   // time

__device__ __forceinline__ float ex2(float x){ return __builtin_amdgcn_exp2f(x); }
__device__ __forceinline__ float lg2(float x){ return __builtin_amdgcn_logf(x); }
__device__ __forceinline__ float rcpf(float x){ return __builtin_amdgcn_rcpf(x); }
// wave-uniform value -> SGPR (VALU allows 1 SGPR source per instruction)
__device__ __forceinline__ float rfl(float x){
    return __uint_as_float(__builtin_amdgcn_readfirstlane(__float_as_uint(x)));
}

constexpr float kLog2e = 1.4426950408889634f;
constexpr float kLn2   = 0.6931471805599453f;

__device__ __forceinline__ float fast_tanh(float x){
    float ax = fabsf(x);
    float e  = ex2(ax * (-2.0f * kLog2e));     // exp(-2|x|)
    float t  = (1.0f - e) * rcpf(1.0f + e);
    return copysignf(t, x);
}

__device__ __forceinline__ float sel4(float v0, float v1, float v2, float v3, int idx){
    float r = (idx == 1) ? v1 : v0;
    r = (idx == 2) ? v2 : r;
    r = (idx == 3) ? v3 : r;
    return r;
}

struct P1Params {
    float AL[4][4], M[4][4];      // SGPR-resident (rfl'd)
    float wsv[4], wwv[4], wnv[4]; // SGPR-resident
    float bwc, bnc;
    const float* sA; const float* sM;
};

// one generic CRF step, NCOL=4 (exp-space)
__device__ __forceinline__ void step4(
    const P1Params& pp, float fi0, float fi1, float fi2, float fi3,
    float bv, int tg, bool renorm,
    float (&P)[4][4], float (&lacc)[4], float& gold, int& prev)
{
    const bool hw = bv > 0.5f;
    const float bc = hw ? pp.bwc : pp.bnc;
    float g[4], gL[4];
    #pragma unroll
    for (int j = 0; j < 4; ++j) {
        float x = fmaf(bv, pp.wsv[j], bc);
        g[j]  = (hw ? pp.wwv[j] : pp.wnv[j]) * fast_tanh(x);
        gL[j] = g[j] * kLog2e;
    }
    const float fiL[4] = { fi0 * kLog2e, fi1 * kLog2e, fi2 * kLog2e, fi3 * kLog2e };
    float nP[4][4];
    #pragma unroll
    for (int i = 0; i < 4; ++i)
        #pragma unroll
        for (int j = 0; j < 4; ++j) nP[i][j] = 0.0f;
    #pragma unroll
    for (int k = 0; k < 4; ++k) {
        float Ek[4];
        #pragma unroll
        for (int i = 0; i < 4; ++i)
            Ek[i] = ex2(fmaf(gL[k], pp.M[i][k], fiL[i] + pp.AL[i][k]));
        #pragma unroll
        for (int j = 0; j < 4; ++j) {
            const float pk = P[k][j];
            #pragma unroll
            for (int i = 0; i < 4; ++i) nP[i][j] = fmaf(Ek[i], pk, nP[i][j]);
        }
    }
    #pragma unroll
    for (int i = 0; i < 4; ++i)
        #pragma unroll
        for (int j = 0; j < 4; ++j) P[i][j] = nP[i][j];

    const int idx = tg * 4 + prev;
    gold += pp.sA[idx] + sel4(g[0], g[1], g[2], g[3], prev) * pp.sM[idx]
          + sel4(fi0, fi1, fi2, fi3, tg);
    prev = tg;

    if (renorm) {     // exact pow2 renorm
        #pragma unroll
        for (int j = 0; j < 4; ++j) {
            float m = fmaxf(fmaxf(P[0][j], P[1][j]), fmaxf(P[2][j], P[3][j]));
            int ee = (int)((__float_as_uint(m) >> 23) & 255u) - 126;
            float sc = __uint_as_float((unsigned)(127 - ee) << 23);
            lacc[j] += (float)ee;
            #pragma unroll
            for (int i = 0; i < 4; ++i) P[i][j] *= sc;
        }
    }
}

// first step from identity: P = E directly (bit-identical to step4 from I)
__device__ __forceinline__ void step_first(
    const P1Params& pp, float fi0, float fi1, float fi2, float fi3,
    float bv, int tg, float (&P)[4][4], float& gold, int& prev)
{
    const bool hw = bv > 0.5f;
    const float bc = hw ? pp.bwc : pp.bnc;
    float g[4], gL[4];
    #pragma unroll
    for (int j = 0; j < 4; ++j) {
        float x = fmaf(bv, pp.wsv[j], bc);
        g[j]  = (hw ? pp.wwv[j] : pp.wnv[j]) * fast_tanh(x);
        gL[j] = g[j] * kLog2e;
    }
    const float fiL[4] = { fi0 * kLog2e, fi1 * kLog2e, fi2 * kLog2e, fi3 * kLog2e };
    #pragma unroll
    for (int i = 0; i < 4; ++i)
        #pragma unroll
        for (int j = 0; j < 4; ++j)
            P[i][j] = ex2(fmaf(gL[j], pp.M[i][j], fiL[i] + pp.AL[i][j]));
    const int idx = tg * 4 + prev;
    gold += pp.sA[idx] + sel4(g[0], g[1], g[2], g[3], prev) * pp.sM[idx]
          + sel4(fi0, fi1, fi2, fi3, tg);
    prev = tg;
}

// C = A∘B (A later, B earlier) in exp-space with per-column base-2 offsets.
__device__ __forceinline__ void compose4(
    const float (&Ae)[4][4], const float (&sa)[4],
    const float (&Be)[4][4], const float (&sb)[4],
    float (&Ce)[4][4], float (&sc)[4])
{
    const float maxA = fmaxf(fmaxf(sa[0], sa[1]), fmaxf(sa[2], sa[3]));
    float Ap[4][4];
    #pragma unroll
    for (int k = 0; k < 4; ++k) {
        const float wk = ex2(sa[k] - maxA);
        #pragma unroll
        for (int i = 0; i < 4; ++i) Ap[i][k] = Ae[i][k] * wk;
    }
    #pragma unroll
    for (int j = 0; j < 4; ++j) {
        float c0 = 0.f, c1 = 0.f, c2 = 0.f, c3 = 0.f;
        #pragma unroll
        for (int k = 0; k < 4; ++k) {
            const float bk = Be[k][j];
            c0 = fmaf(Ap[0][k], bk, c0);
            c1 = fmaf(Ap[1][k], bk, c1);
            c2 = fmaf(Ap[2][k], bk, c2);
            c3 = fmaf(Ap[3][k], bk, c3);
        }
        const float m = fmaxf(fmaxf(c0, c1), fmaxf(c2, c3));
        const int ee = (int)((__float_as_uint(m) >> 23) & 255u) - 126;
        const float scf = __uint_as_float((unsigned)(127 - ee) << 23);
        Ce[0][j] = c0 * scf; Ce[1][j] = c1 * scf;
        Ce[2][j] = c2 * scf; Ce[3][j] = c3 * scf;
        sc[j] = sb[j] + maxA + (float)ee;
    }
}

// ============ FUSED: 128 threads = 1 batch; 128 chunks x 16 steps ============
// 2x work per thread amortizes prologue/tree/setup; grid 4096 waves = 4/SIMD
// fully resident for any VGPR <= 128 (no launch-bounds forcing after r10).
__global__ void __launch_bounds__(128)
crf_fused(const float* __restrict__ feats, const float* __restrict__ bias,
          const int* __restrict__ tags, const float* __restrict__ trans,
          const float* __restrict__ wsh, const float* __restrict__ bno,
          const float* __restrict__ bwi, const float* __restrict__ wwo,
          const float* __restrict__ wno, const float* __restrict__ mult,
          float* __restrict__ out)
{
    const int w = threadIdx.x >> 6;     // wave 0..1
    const int L = threadIdx.x & 63;     // lane = local chunk
    const int b = blockIdx.x;
    const int c = threadIdx.x;          // chunk id 0..127 (16 steps each)

    // 1600 floats = 6.4 KB: staging (2 waves x 192 float4 = 6144 B) overlaid
    // by the 64 x 25-float reduction slots (6400 B).
    __shared__ float shm[1600];
    __shared__ float sA[20], sM[16];    // sA[16..19] = trans[i*6+4] (init column)
    float4* stageW = ((float4*)shm) + w * 192;

    if (threadIdx.x < 16) {
        const int i = threadIdx.x >> 2, j = threadIdx.x & 3;
        sA[threadIdx.x] = trans[i * 6 + j];
        const float m0 = mult[j], m1 = mult[4 + j], m2 = mult[8 + j], m3 = mult[12 + j];
        const float mx = fmaxf(fmaxf(m0, m1), fmaxf(m2, m3));
        const float e0 = ex2((m0 - mx) * kLog2e), e1 = ex2((m1 - mx) * kLog2e);
        const float e2 = ex2((m2 - mx) * kLog2e), e3 = ex2((m3 - mx) * kLog2e);
        const float inv = rcpf(e0 + e1 + e2 + e3);
        const float ei = (i == 0) ? e0 : (i == 1) ? e1 : (i == 2) ? e2 : e3;
        sM[threadIdx.x] = (i == j) ? -1.0f : ei * inv;
        if (threadIdx.x < 4) sA[16 + threadIdx.x] = trans[threadIdx.x * 6 + 4];
    }
    __syncthreads();

    // wave-uniform constants -> SGPRs
    P1Params pp;
    #pragma unroll
    for (int i = 0; i < 4; ++i)
        #pragma unroll
        for (int j = 0; j < 4; ++j) {
            pp.AL[i][j] = rfl(trans[i * 6 + j] * kLog2e);
            pp.M[i][j]  = rfl(sM[i * 4 + j]);
        }
    #pragma unroll
    for (int j = 0; j < 4; ++j) {
        pp.wsv[j] = rfl(wsh[j]); pp.wwv[j] = rfl(wwo[j]); pp.wnv[j] = rfl(wno[j]);
    }
    pp.bwc = rfl(bwi[0]); pp.bnc = rfl(bno[0]);
    pp.sA = sA; pp.sM = sM;
    const float tcI0 = rfl(sA[16]), tcI1 = rfl(sA[17]);
    const float tcI2 = rfl(sA[18]), tcI3 = rfl(sA[19]);

    int prev = 0;
    if (c != 0) prev = tags[(size_t)b * TN + c * 16 - 1];

    // wave's feats window: 64 chunks x 24 float4; chunk cl owns [24*cl, 24*cl+24)
    const float4* gF = (const float4*)feats + (size_t)b * 3072 + (size_t)w * 1536;
    const float* bbase = bias + (size_t)b * TN + c * 16;
    const int*   tbase = tags + (size_t)b * TN + c * 16;

    // per-lane staged-load base indices (stage s adds +3*s, s in [0,8))
    int off[3];
    #pragma unroll
    for (int r = 0; r < 3; ++r) {
        const int S = r * 64 + L, cS = (S * 21846) >> 16;   // S/3, exact for S<192
        off[r] = cS * 24 + (S - cS * 3);
    }

    float P[4][4], lacc[4] = {0.f, 0.f, 0.f, 0.f};
    float gold = 0.0f;
    const bool isC0 = (c == 0);

    // ---- prologue: issue stages 0,1 (depth-2 pipeline) ----
    float4 tF0[3], tF1[3]; float2 bvA, bvB; int2 tgA, tgB;
    #pragma unroll
    for (int r = 0; r < 3; ++r) { tF0[r] = gF[off[r]]; tF1[r] = gF[off[r] + 3]; }
    bvA = *(const float2*)(bbase);     tgA = *(const int2*)(tbase);
    bvB = *(const float2*)(bbase + 2); tgB = *(const int2*)(tbase + 2);

    #pragma unroll 1
    for (int sp = 0; sp < 4; ++sp) {    // stage-pair: stages 2sp (A), 2sp+1 (B)
        // ================= stage A (global steps 4sp, 4sp+1) =================
        #pragma unroll
        for (int r = 0; r < 3; ++r) {
            const int S = r * 64 + L, cS = (S * 21846) >> 16, j = S - cS * 3;
            stageW[(j << 6) + ((cS + j) & 63)] = tF0[r];
        }
        {
            const float bvx = bvA.x, bvy = bvA.y;
            const int   tgx = tgA.x, tgy = tgA.y;
            if (sp < 3) {   // prefetch stage 2sp+2 into buffer 0
                #pragma unroll
                for (int r = 0; r < 3; ++r) tF0[r] = gF[off[r] + 6 * sp + 6];
                bvA = *(const float2*)(bbase + 4 * sp + 4);
                tgA = *(const int2*)(tbase + 4 * sp + 4);
            }
            const float4 fA = stageW[(0 << 6) + ( L      & 63)];
            const float4 fB = stageW[(1 << 6) + ((L + 1) & 63)];
            const float4 fC = stageW[(2 << 6) + ((L + 2) & 63)];
            {   // global step 4sp
                const float fi0 = fA.x, fi1 = fA.y, fi2 = fA.z, fi3 = fA.w;
                if (sp == 0) {
                    if (isC0) {   // rank-1 closed-form t=0
                        const float a0 = fi0 + tcI0, a1 = fi1 + tcI1;
                        const float a2 = fi2 + tcI2, a3 = fi3 + tcI3;
                        const float mx = fmaxf(fmaxf(a0, a1), fmaxf(a2, a3));
                        const float e0 = ex2((a0 - mx) * kLog2e);
                        const float e1 = ex2((a1 - mx) * kLog2e);
                        const float e2 = ex2((a2 - mx) * kLog2e);
                        const float e3 = ex2((a3 - mx) * kLog2e);
                        #pragma unroll
                        for (int j = 0; j < 4; ++j) {
                            P[0][j] = e0; P[1][j] = e1; P[2][j] = e2; P[3][j] = e3;
                            lacc[j] = mx * kLog2e;
                        }
                        gold = sel4(tcI0, tcI1, tcI2, tcI3, tgx)
                             + sel4(fi0, fi1, fi2, fi3, tgx);
                        prev = tgx;
                    } else {      // P = E directly (identity start, bit-exact)
                        step_first(pp, fi0, fi1, fi2, fi3, bvx, tgx, P, gold, prev);
                    }
                } else {
                    step4(pp, fi0, fi1, fi2, fi3, bvx, tgx, false, P, lacc, gold, prev);
                }
            }
            {   // global step 4sp+1 (never renorm: (4sp+1)&3 == 1)
                const float fi0 = fB.z, fi1 = fB.w, fi2 = fC.x, fi3 = fC.y;
                step4(pp, fi0, fi1, fi2, fi3, bvy, tgy, false, P, lacc, gold, prev);
            }
        }
        // ================= stage B (global steps 4sp+2, 4sp+3) =================
        #pragma unroll
        for (int r = 0; r < 3; ++r) {
            const int S = r * 64 + L, cS = (S * 21846) >> 16, j = S - cS * 3;
            stageW[(j << 6) + ((cS + j) & 63)] = tF1[r];
        }
        {
            const float bvx = bvB.x, bvy = bvB.y;
            const int   tgx = tgB.x, tgy = tgB.y;
            if (sp < 3) {   // prefetch stage 2sp+3 into buffer 1
                #pragma unroll
                for (int r = 0; r < 3; ++r) tF1[r] = gF[off[r] + 6 * sp + 9];
                bvB = *(const float2*)(bbase + 4 * sp + 6);
                tgB = *(const int2*)(tbase + 4 * sp + 6);
            }
            const float4 fA = stageW[(0 << 6) + ( L      & 63)];
            const float4 fB = stageW[(1 << 6) + ((L + 1) & 63)];
            const float4 fC = stageW[(2 << 6) + ((L + 2) & 63)];
            {   // global step 4sp+2
                const float fi0 = fA.x, fi1 = fA.y, fi2 = fA.z, fi3 = fA.w;
                step4(pp, fi0, fi1, fi2, fi3, bvx, tgx, false, P, lacc, gold, prev);
            }
            {   // global step 4sp+3: renorm (≡3 mod 4)
                const float fi0 = fB.z, fi1 = fB.w, fi2 = fC.x, fi3 = fC.y;
                step4(pp, fi0, fi1, fi2, fi3, bvy, tgy, true, P, lacc, gold, prev);
            }
        }
    }

    // ---- tree level 0 in registers via shuffle (pairs (c, c+1), same wave) ----
    {
        float oP[4][4], os[4];
        #pragma unroll
        for (int i = 0; i < 4; ++i)
            #pragma unroll
            for (int j = 0; j < 4; ++j) oP[i][j] = __shfl_xor(P[i][j], 1, 64);
        #pragma unroll
        for (int j = 0; j < 4; ++j) os[j] = __shfl_xor(lacc[j], 1, 64);
        const float og = __shfl_xor(gold, 1, 64);
        // even lane: own = earlier (chunk c), partner = later (chunk c+1)
        float Ce[4][4], sc[4];
        compose4(oP, os, P, lacc, Ce, sc);
        #pragma unroll
        for (int i = 0; i < 4; ++i)
            #pragma unroll
            for (int j = 0; j < 4; ++j) P[i][j] = Ce[i][j];
        #pragma unroll
        for (int j = 0; j < 4; ++j) lacc[j] = sc[j];
        gold += og;                     // meaningful on even lanes only
    }

    // ---- write 64 pair-results; then 6 LDS levels ----
    __syncthreads();                    // all staging reads done; safe to overlay
    if ((c & 1) == 0) {
        float* my = shm + (size_t)(c >> 1) * 25;
        #pragma unroll
        for (int i = 0; i < 4; ++i)
            #pragma unroll
            for (int j = 0; j < 4; ++j) my[i * 4 + j] = P[i][j];
        #pragma unroll
        for (int j = 0; j < 4; ++j) my[16 + j] = lacc[j];
        my[20] = gold;
    }
    #pragma unroll 1
    for (int l = 0; l < 6; ++l) {
        __syncthreads();
        const int cnt = 32 >> l;
        if (threadIdx.x < cnt) {
            float* se = shm + (size_t)(threadIdx.x << (l + 1)) * 25;  // earlier
            const float* sl = se + (25 << l);                         // later
            float Be_[4][4], sb[4], Ae[4][4], sa[4];
            #pragma unroll
            for (int i = 0; i < 4; ++i)
                #pragma unroll
                for (int j = 0; j < 4; ++j) { Be_[i][j] = se[i*4+j]; Ae[i][j] = sl[i*4+j]; }
            #pragma unroll
            for (int j = 0; j < 4; ++j) { sb[j] = se[16+j]; sa[j] = sl[16+j]; }
            const float gsum = se[20] + sl[20];
            float Ce[4][4], sc[4];
            compose4(Ae, sa, Be_, sb, Ce, sc);     // later ∘ earlier
            #pragma unroll
            for (int i = 0; i < 4; ++i)
                #pragma unroll
                for (int j = 0; j < 4; ++j) se[i*4+j] = Ce[i][j];
            #pragma unroll
            for (int j = 0; j < 4; ++j) se[16+j] = sc[j];
            se[20] = gsum;
        }
    }

    if (threadIdx.x == 0) {             // slot 0 was written by this thread
        const float p00 = shm[0], p10 = shm[4], p20 = shm[8], p30 = shm[12];
        const float so0 = shm[16];
        const float gall = shm[20];
        const float t50 = trans[30], t51 = trans[31], t52 = trans[32], t53 = trans[33];
        const float ssum = p00 * ex2(t50 * kLog2e) + p10 * ex2(t51 * kLog2e)
                         + p20 * ex2(t52 * kLog2e) + p30 * ex2(t53 * kLog2e);
        const float fwd = (so0 + lg2(ssum)) * kLn2;
        const int lastT = tags[(size_t)b * TN + TN - 1];
        const float gfin = gall + sel4(t50, t51, t52, t53, lastT);
        out[b] = fwd - gfin;
    }
}

extern "C" void kernel_launch(void* const* d_in, const int* in_sizes, int n_in,
                              void* d_out, int out_size, void* d_ws, size_t ws_size,
                              hipStream_t stream)
{
    const float* feats = (const float*)d_in[0];
    const float* bias  = (const float*)d_in[1];
    const int*   tags  = (const int*)d_in[2];
    const float* trans = (const float*)d_in[3];
    const float* wsh   = (const float*)d_in[4];
    const float* bno   = (const float*)d_in[5];
    const float* bwi   = (const float*)d_in[6];
    const float* wwo   = (const float*)d_in[7];
    const float* wno   = (const float*)d_in[8];
    const float* mult  = (const float*)d_in[9];
    float* out = (float*)d_out;
    (void)d_ws; (void)ws_size;   // workspace not needed

    crf_fused<<<BN, 128, 0, stream>>>(
        feats, bias, tags, trans, wsh, bno, bwi, wwo, wno, mult, out);
}

// Round 12
// 195.909 us; speedup vs baseline: 1.5456x; 1.2892x over previous
//
#include <hip/hip_runtime.h>

#define BN 2048   // batch
#define TN 2048   // time

__device__ __forceinline__ float ex2(float x){ return __builtin_amdgcn_exp2f(x); }
__device__ __forceinline__ float lg2(float x){ return __builtin_amdgcn_logf(x); }
__device__ __forceinline__ float rcpf(float x){ return __builtin_amdgcn_rcpf(x); }
// wave-uniform value -> SGPR (VALU allows 1 SGPR source per instruction)
__device__ __forceinline__ float rfl(float x){
    return __uint_as_float(__builtin_amdgcn_readfirstlane(__float_as_uint(x)));
}

constexpr float kLog2e = 1.4426950408889634f;
constexpr float kLn2   = 0.6931471805599453f;

__device__ __forceinline__ float fast_tanh(float x){
    float ax = fabsf(x);
    float e  = ex2(ax * (-2.0f * kLog2e));     // exp(-2|x|)
    float t  = (1.0f - e) * rcpf(1.0f + e);
    return copysignf(t, x);
}

__device__ __forceinline__ float sel4(float v0, float v1, float v2, float v3, int idx){
    float r = (idx == 1) ? v1 : v0;
    r = (idx == 2) ? v2 : r;
    r = (idx == 3) ? v3 : r;
    return r;
}

struct P1Params {
    float AL[4][4], M[4][4];      // SGPR-resident (rfl'd)
    float wsv[4], wwv[4], wnv[4]; // SGPR-resident
    float bwc, bnc;
    const float* sA; const float* sM;
};

// one generic CRF step, NCOL=4 (exp-space)
__device__ __forceinline__ void step4(
    const P1Params& pp, float fi0, float fi1, float fi2, float fi3,
    float bv, int tg, bool renorm,
    float (&P)[4][4], float (&lacc)[4], float& gold, int& prev)
{
    const bool hw = bv > 0.5f;
    const float bc = hw ? pp.bwc : pp.bnc;
    float g[4], gL[4];
    #pragma unroll
    for (int j = 0; j < 4; ++j) {
        float x = fmaf(bv, pp.wsv[j], bc);
        g[j]  = (hw ? pp.wwv[j] : pp.wnv[j]) * fast_tanh(x);
        gL[j] = g[j] * kLog2e;
    }
    const float fiL[4] = { fi0 * kLog2e, fi1 * kLog2e, fi2 * kLog2e, fi3 * kLog2e };
    float nP[4][4];
    #pragma unroll
    for (int i = 0; i < 4; ++i)
        #pragma unroll
        for (int j = 0; j < 4; ++j) nP[i][j] = 0.0f;
    #pragma unroll
    for (int k = 0; k < 4; ++k) {
        float Ek[4];
        #pragma unroll
        for (int i = 0; i < 4; ++i)
            Ek[i] = ex2(fmaf(gL[k], pp.M[i][k], fiL[i] + pp.AL[i][k]));
        #pragma unroll
        for (int j = 0; j < 4; ++j) {
            const float pk = P[k][j];
            #pragma unroll
            for (int i = 0; i < 4; ++i) nP[i][j] = fmaf(Ek[i], pk, nP[i][j]);
        }
    }
    #pragma unroll
    for (int i = 0; i < 4; ++i)
        #pragma unroll
        for (int j = 0; j < 4; ++j) P[i][j] = nP[i][j];

    const int idx = tg * 4 + prev;
    gold += pp.sA[idx] + sel4(g[0], g[1], g[2], g[3], prev) * pp.sM[idx]
          + sel4(fi0, fi1, fi2, fi3, tg);
    prev = tg;

    if (renorm) {     // exact pow2 renorm
        #pragma unroll
        for (int j = 0; j < 4; ++j) {
            float m = fmaxf(fmaxf(P[0][j], P[1][j]), fmaxf(P[2][j], P[3][j]));
            int ee = (int)((__float_as_uint(m) >> 23) & 255u) - 126;
            float sc = __uint_as_float((unsigned)(127 - ee) << 23);
            lacc[j] += (float)ee;
            #pragma unroll
            for (int i = 0; i < 4; ++i) P[i][j] *= sc;
        }
    }
}

// C = A∘B (A later, B earlier) in exp-space with per-column base-2 offsets.
__device__ __forceinline__ void compose4(
    const float (&Ae)[4][4], const float (&sa)[4],
    const float (&Be)[4][4], const float (&sb)[4],
    float (&Ce)[4][4], float (&sc)[4])
{
    const float maxA = fmaxf(fmaxf(sa[0], sa[1]), fmaxf(sa[2], sa[3]));
    float Ap[4][4];
    #pragma unroll
    for (int k = 0; k < 4; ++k) {
        const float wk = ex2(sa[k] - maxA);
        #pragma unroll
        for (int i = 0; i < 4; ++i) Ap[i][k] = Ae[i][k] * wk;
    }
    #pragma unroll
    for (int j = 0; j < 4; ++j) {
        float c0 = 0.f, c1 = 0.f, c2 = 0.f, c3 = 0.f;
        #pragma unroll
        for (int k = 0; k < 4; ++k) {
            const float bk = Be[k][j];
            c0 = fmaf(Ap[0][k], bk, c0);
            c1 = fmaf(Ap[1][k], bk, c1);
            c2 = fmaf(Ap[2][k], bk, c2);
            c3 = fmaf(Ap[3][k], bk, c3);
        }
        const float m = fmaxf(fmaxf(c0, c1), fmaxf(c2, c3));
        const int ee = (int)((__float_as_uint(m) >> 23) & 255u) - 126;
        const float scf = __uint_as_float((unsigned)(127 - ee) << 23);
        Ce[0][j] = c0 * scf; Ce[1][j] = c1 * scf;
        Ce[2][j] = c2 * scf; Ce[3][j] = c3 * scf;
        sc[j] = sb[j] + maxA + (float)ee;
    }
}

// ============ FUSED: 1 block = 1 batch; depth-3 2-step pipeline + shfl+LDS tree ============
// Best measured configuration (round 9): kernel ~65 us, total ~197 us.
__global__ void __launch_bounds__(256)
crf_fused(const float* __restrict__ feats, const float* __restrict__ bias,
          const int* __restrict__ tags, const float* __restrict__ trans,
          const float* __restrict__ wsh, const float* __restrict__ bno,
          const float* __restrict__ bwi, const float* __restrict__ wwo,
          const float* __restrict__ wno, const float* __restrict__ mult,
          float* __restrict__ out)
{
    const int w = threadIdx.x >> 6;     // wave 0..3
    const int L = threadIdx.x & 63;     // lane = local chunk
    const int b = blockIdx.x;
    const int c = threadIdx.x;          // global chunk id 0..255

    // 3200 floats = 12.8 KB: staging (4 waves x 192 float4 = 12288 B) overlaid
    // by the 128 x 25-float reduction slots (12800 B).
    __shared__ float shm[3200];
    __shared__ float sA[20], sM[16];    // sA[16..19] = trans[i*6+4] (init column)
    float4* stageW = ((float4*)shm) + w * 192;

    if (threadIdx.x < 16) {
        const int i = threadIdx.x >> 2, j = threadIdx.x & 3;
        sA[threadIdx.x] = trans[i * 6 + j];
        const float m0 = mult[j], m1 = mult[4 + j], m2 = mult[8 + j], m3 = mult[12 + j];
        const float mx = fmaxf(fmaxf(m0, m1), fmaxf(m2, m3));
        const float e0 = ex2((m0 - mx) * kLog2e), e1 = ex2((m1 - mx) * kLog2e);
        const float e2 = ex2((m2 - mx) * kLog2e), e3 = ex2((m3 - mx) * kLog2e);
        const float inv = rcpf(e0 + e1 + e2 + e3);
        const float ei = (i == 0) ? e0 : (i == 1) ? e1 : (i == 2) ? e2 : e3;
        sM[threadIdx.x] = (i == j) ? -1.0f : ei * inv;
        if (threadIdx.x < 4) sA[16 + threadIdx.x] = trans[threadIdx.x * 6 + 4];
    }
    __syncthreads();

    // wave-uniform constants -> SGPRs
    P1Params pp;
    #pragma unroll
    for (int i = 0; i < 4; ++i)
        #pragma unroll
        for (int j = 0; j < 4; ++j) {
            pp.AL[i][j] = rfl(trans[i * 6 + j] * kLog2e);
            pp.M[i][j]  = rfl(sM[i * 4 + j]);
        }
    #pragma unroll
    for (int j = 0; j < 4; ++j) {
        pp.wsv[j] = rfl(wsh[j]); pp.wwv[j] = rfl(wwo[j]); pp.wnv[j] = rfl(wno[j]);
    }
    pp.bwc = rfl(bwi[0]); pp.bnc = rfl(bno[0]);
    pp.sA = sA; pp.sM = sM;
    const float tcI0 = rfl(sA[16]), tcI1 = rfl(sA[17]);
    const float tcI2 = rfl(sA[18]), tcI3 = rfl(sA[19]);

    int prev = 0;
    if (c != 0) prev = tags[(size_t)b * TN + c * 8 - 1];

    // wave's feats window: 64 chunks x 12 float4; chunk cl owns [12*cl, 12*cl+12)
    const float4* gF = (const float4*)feats + (size_t)b * 3072 + (size_t)w * 768;
    const float* bbase = bias + (size_t)b * TN + c * 8;
    const int*   tbase = tags + (size_t)b * TN + c * 8;

    // per-lane staged-load base indices (stage s adds +3*s)
    int off[3];
    #pragma unroll
    for (int r = 0; r < 3; ++r) {
        const int S = r * 64 + L, cS = (S * 21846) >> 16;   // S/3, exact for S<192
        off[r] = cS * 12 + (S - cS * 3);
    }

    float P[4][4], lacc[4] = {0.f, 0.f, 0.f, 0.f};
    #pragma unroll
    for (int i = 0; i < 4; ++i)
        #pragma unroll
        for (int j = 0; j < 4; ++j) P[i][j] = (i == j) ? 1.0f : 0.0f;
    float gold = 0.0f;
    const bool isC0 = (c == 0);

    // ---- prologue: issue stages 0..2 (depth-3 pipeline) ----
    float4 tF[4][3]; float2 bv2[4]; int2 tg2[4];
    #pragma unroll
    for (int s = 0; s < 3; ++s) {
        #pragma unroll
        for (int r = 0; r < 3; ++r) tF[s][r] = gF[off[r] + s * 3];
        bv2[s] = *(const float2*)(bbase + 2 * s);
        tg2[s] = *(const int2*)(tbase + 2 * s);
    }

    #pragma unroll
    for (int s = 0; s < 4; ++s) {
        // transpose stage s into wave-private LDS (vmcnt wait lands here)
        #pragma unroll
        for (int r = 0; r < 3; ++r) {
            const int S = r * 64 + L, cS = (S * 21846) >> 16, j = S - cS * 3;
            stageW[(j << 6) + ((cS + j) & 63)] = tF[s][r];
        }
        if (s == 0) {   // issue stage 3 (stays in flight across stages 0..2)
            #pragma unroll
            for (int r = 0; r < 3; ++r) tF[3][r] = gF[off[r] + 9];
            bv2[3] = *(const float2*)(bbase + 6);
            tg2[3] = *(const int2*)(tbase + 6);
        }
        const float4 fA = stageW[(0 << 6) + ( L      & 63)];
        const float4 fB = stageW[(1 << 6) + ((L + 1) & 63)];
        const float4 fC = stageW[(2 << 6) + ((L + 2) & 63)];
        {   // step 2s : floats 12s+0..3
            const float fi0 = fA.x, fi1 = fA.y, fi2 = fA.z, fi3 = fA.w;
            if (isC0 && s == 0) {
                const float a0 = fi0 + tcI0, a1 = fi1 + tcI1;
                const float a2 = fi2 + tcI2, a3 = fi3 + tcI3;
                const float mx = fmaxf(fmaxf(a0, a1), fmaxf(a2, a3));
                const float e0 = ex2((a0 - mx) * kLog2e);
                const float e1 = ex2((a1 - mx) * kLog2e);
                const float e2 = ex2((a2 - mx) * kLog2e);
                const float e3 = ex2((a3 - mx) * kLog2e);
                #pragma unroll
                for (int j = 0; j < 4; ++j) {
                    P[0][j] = e0; P[1][j] = e1; P[2][j] = e2; P[3][j] = e3;
                    lacc[j] = mx * kLog2e;
                }
                const int tg0 = tg2[0].x;
                gold = sel4(tcI0, tcI1, tcI2, tcI3, tg0)
                     + sel4(fi0, fi1, fi2, fi3, tg0);
                prev = tg0;
            } else {
                step4(pp, fi0, fi1, fi2, fi3, bv2[s].x, tg2[s].x,
                      false, P, lacc, gold, prev);
            }
        }
        {   // step 2s+1 : floats 12s+6..9 ; renorm when (2s+1)&3==3 i.e. s odd
            const float fi0 = fB.z, fi1 = fB.w, fi2 = fC.x, fi3 = fC.y;
            step4(pp, fi0, fi1, fi2, fi3, bv2[s].y, tg2[s].y,
                  (s & 1) == 1, P, lacc, gold, prev);
        }
    }

    // ---- tree level 0 in registers via shuffle (same binary topology) ----
    {
        float oP[4][4], os[4];
        #pragma unroll
        for (int i = 0; i < 4; ++i)
            #pragma unroll
            for (int j = 0; j < 4; ++j) oP[i][j] = __shfl_xor(P[i][j], 1, 64);
        #pragma unroll
        for (int j = 0; j < 4; ++j) os[j] = __shfl_xor(lacc[j], 1, 64);
        const float og = __shfl_xor(gold, 1, 64);
        // even lane: own = earlier (chunk c), partner = later (chunk c+1)
        float Ce[4][4], sc[4];
        compose4(oP, os, P, lacc, Ce, sc);
        #pragma unroll
        for (int i = 0; i < 4; ++i)
            #pragma unroll
            for (int j = 0; j < 4; ++j) P[i][j] = Ce[i][j];
        #pragma unroll
        for (int j = 0; j < 4; ++j) lacc[j] = sc[j];
        gold += og;                     // meaningful on even lanes only
    }

    // ---- write 128 pair-results; then 7 LDS levels ----
    __syncthreads();                    // all staging reads done; safe to overlay
    if ((c & 1) == 0) {
        float* my = shm + (size_t)(c >> 1) * 25;
        #pragma unroll
        for (int i = 0; i < 4; ++i)
            #pragma unroll
            for (int j = 0; j < 4; ++j) my[i * 4 + j] = P[i][j];
        #pragma unroll
        for (int j = 0; j < 4; ++j) my[16 + j] = lacc[j];
        my[20] = gold;
    }
    #pragma unroll 1
    for (int l = 0; l < 7; ++l) {
        __syncthreads();
        const int cnt = 64 >> l;
        if (threadIdx.x < cnt) {
            float* se = shm + (size_t)(threadIdx.x << (l + 1)) * 25;  // earlier
            const float* sl = se + (25 << l);                         // later
            float Be_[4][4], sb[4], Ae[4][4], sa[4];
            #pragma unroll
            for (int i = 0; i < 4; ++i)
                #pragma unroll
                for (int j = 0; j < 4; ++j) { Be_[i][j] = se[i*4+j]; Ae[i][j] = sl[i*4+j]; }
            #pragma unroll
            for (int j = 0; j < 4; ++j) { sb[j] = se[16+j]; sa[j] = sl[16+j]; }
            const float gsum = se[20] + sl[20];
            float Ce[4][4], sc[4];
            compose4(Ae, sa, Be_, sb, Ce, sc);     // later ∘ earlier
            #pragma unroll
            for (int i = 0; i < 4; ++i)
                #pragma unroll
                for (int j = 0; j < 4; ++j) se[i*4+j] = Ce[i][j];
            #pragma unroll
            for (int j = 0; j < 4; ++j) se[16+j] = sc[j];
            se[20] = gsum;
        }
    }

    if (threadIdx.x == 0) {             // slot 0 was written by this thread
        const float p00 = shm[0], p10 = shm[4], p20 = shm[8], p30 = shm[12];
        const float so0 = shm[16];
        const float gall = shm[20];
        const float t50 = trans[30], t51 = trans[31], t52 = trans[32], t53 = trans[33];
        const float ssum = p00 * ex2(t50 * kLog2e) + p10 * ex2(t51 * kLog2e)
                         + p20 * ex2(t52 * kLog2e) + p30 * ex2(t53 * kLog2e);
        const float fwd = (so0 + lg2(ssum)) * kLn2;
        const int lastT = tags[(size_t)b * TN + TN - 1];
        const float gfin = gall + sel4(t50, t51, t52, t53, lastT);
        out[b] = fwd - gfin;
    }
}

extern "C" void kernel_launch(void* const* d_in, const int* in_sizes, int n_in,
                              void* d_out, int out_size, void* d_ws, size_t ws_size,
                              hipStream_t stream)
{
    const float* feats = (const float*)d_in[0];
    const float* bias  = (const float*)d_in[1];
    const int*   tags  = (const int*)d_in[2];
    const float* trans = (const float*)d_in[3];
    const float* wsh   = (const float*)d_in[4];
    const float* bno   = (const float*)d_in[5];
    const float* bwi   = (const float*)d_in[6];
    const float* wwo   = (const float*)d_in[7];
    const float* wno   = (const float*)d_in[8];
    const float* mult  = (const float*)d_in[9];
    float* out = (float*)d_out;
    (void)d_ws; (void)ws_size;   // workspace not needed

    crf_fused<<<BN, 256, 0, stream>>>(
        feats, bias, tags, trans, wsh, bno, bwi, wwo, wno, mult, out);
}

// Round 13
// 191.791 us; speedup vs baseline: 1.5788x; 1.0215x over previous
//
#include <hip/hip_runtime.h>

#define BN 2048   // batch
#define TN 2048   // time

__device__ __forceinline__ float ex2(float x){ return __builtin_amdgcn_exp2f(x); }
__device__ __forceinline__ float lg2(float x){ return __builtin_amdgcn_logf(x); }
__device__ __forceinline__ float rcpf(float x){ return __builtin_amdgcn_rcpf(x); }
// wave-uniform value -> SGPR (VALU allows 1 SGPR source per instruction)
__device__ __forceinline__ float rfl(float x){
    return __uint_as_float(__builtin_amdgcn_readfirstlane(__float_as_uint(x)));
}

constexpr float kLog2e = 1.4426950408889634f;
constexpr float kLn2   = 0.6931471805599453f;

__device__ __forceinline__ float fast_tanh(float x){
    float ax = fabsf(x);
    float e  = ex2(ax * (-2.0f * kLog2e));     // exp(-2|x|)
    float t  = (1.0f - e) * rcpf(1.0f + e);
    return copysignf(t, x);
}

__device__ __forceinline__ float sel4(float v0, float v1, float v2, float v3, int idx){
    float r = (idx == 1) ? v1 : v0;
    r = (idx == 2) ? v2 : r;
    r = (idx == 3) ? v3 : r;
    return r;
}

struct P1Params {
    float AL[4][4], M[4][4];      // SGPR-resident (rfl'd)
    float wsv[4], wwv[4], wnv[4]; // SGPR-resident
    float bwc, bnc;
    const float* sA; const float* sM;
};

// one generic CRF step, NCOL=4 (exp-space). Tag state passed pre-extracted:
// idx = tg*4+prev (transition slot), tg (emission sel), pv (gate sel).
__device__ __forceinline__ void step4(
    const P1Params& pp, float fi0, float fi1, float fi2, float fi3,
    float bv, int idx, int tg, int pv, bool renorm,
    float (&P)[4][4], float (&lacc)[4], float& gold)
{
    const bool hw = bv > 0.5f;
    const float bc = hw ? pp.bwc : pp.bnc;
    float g[4], gL[4];
    #pragma unroll
    for (int j = 0; j < 4; ++j) {
        float x = fmaf(bv, pp.wsv[j], bc);
        g[j]  = (hw ? pp.wwv[j] : pp.wnv[j]) * fast_tanh(x);
        gL[j] = g[j] * kLog2e;
    }
    const float fiL[4] = { fi0 * kLog2e, fi1 * kLog2e, fi2 * kLog2e, fi3 * kLog2e };
    float nP[4][4];
    #pragma unroll
    for (int i = 0; i < 4; ++i)
        #pragma unroll
        for (int j = 0; j < 4; ++j) nP[i][j] = 0.0f;
    #pragma unroll
    for (int k = 0; k < 4; ++k) {
        float Ek[4];
        #pragma unroll
        for (int i = 0; i < 4; ++i)
            Ek[i] = ex2(fmaf(gL[k], pp.M[i][k], fiL[i] + pp.AL[i][k]));
        #pragma unroll
        for (int j = 0; j < 4; ++j) {
            const float pk = P[k][j];
            #pragma unroll
            for (int i = 0; i < 4; ++i) nP[i][j] = fmaf(Ek[i], pk, nP[i][j]);
        }
    }
    #pragma unroll
    for (int i = 0; i < 4; ++i)
        #pragma unroll
        for (int j = 0; j < 4; ++j) P[i][j] = nP[i][j];

    gold += pp.sA[idx] + sel4(g[0], g[1], g[2], g[3], pv) * pp.sM[idx]
          + sel4(fi0, fi1, fi2, fi3, tg);

    if (renorm) {     // exact pow2 renorm
        #pragma unroll
        for (int j = 0; j < 4; ++j) {
            float m = fmaxf(fmaxf(P[0][j], P[1][j]), fmaxf(P[2][j], P[3][j]));
            int ee = (int)((__float_as_uint(m) >> 23) & 255u) - 126;
            float sc = __uint_as_float((unsigned)(127 - ee) << 23);
            lacc[j] += (float)ee;
            #pragma unroll
            for (int i = 0; i < 4; ++i) P[i][j] *= sc;
        }
    }
}

// C = A∘B (A later, B earlier) in exp-space with per-column base-2 offsets.
__device__ __forceinline__ void compose4(
    const float (&Ae)[4][4], const float (&sa)[4],
    const float (&Be)[4][4], const float (&sb)[4],
    float (&Ce)[4][4], float (&sc)[4])
{
    const float maxA = fmaxf(fmaxf(sa[0], sa[1]), fmaxf(sa[2], sa[3]));
    float Ap[4][4];
    #pragma unroll
    for (int k = 0; k < 4; ++k) {
        const float wk = ex2(sa[k] - maxA);
        #pragma unroll
        for (int i = 0; i < 4; ++i) Ap[i][k] = Ae[i][k] * wk;
    }
    #pragma unroll
    for (int j = 0; j < 4; ++j) {
        float c0 = 0.f, c1 = 0.f, c2 = 0.f, c3 = 0.f;
        #pragma unroll
        for (int k = 0; k < 4; ++k) {
            const float bk = Be[k][j];
            c0 = fmaf(Ap[0][k], bk, c0);
            c1 = fmaf(Ap[1][k], bk, c1);
            c2 = fmaf(Ap[2][k], bk, c2);
            c3 = fmaf(Ap[3][k], bk, c3);
        }
        const float m = fmaxf(fmaxf(c0, c1), fmaxf(c2, c3));
        const int ee = (int)((__float_as_uint(m) >> 23) & 255u) - 126;
        const float scf = __uint_as_float((unsigned)(127 - ee) << 23);
        Ce[0][j] = c0 * scf; Ce[1][j] = c1 * scf;
        Ce[2][j] = c2 * scf; Ce[3][j] = c3 * scf;
        sc[j] = sb[j] + maxA + (float)ee;
    }
}

// ============ FUSED: 1 block = 1 batch; depth-3 pipeline + packed-tag VGPR diet ============
// Tag chain packed into ONE register: bits[2t,2t+1]=tag before step t,
// bits[2t+2,2t+3]=tag of step t  =>  idx_t = (packed >> 2t) & 15 = tg*4+prev.
// Targets VGPR <= 64 (8 waves/SIMD band) WITHOUT launch-bounds forcing (r10 lesson).
__global__ void __launch_bounds__(256)
crf_fused(const float* __restrict__ feats, const float* __restrict__ bias,
          const int* __restrict__ tags, const float* __restrict__ trans,
          const float* __restrict__ wsh, const float* __restrict__ bno,
          const float* __restrict__ bwi, const float* __restrict__ wwo,
          const float* __restrict__ wno, const float* __restrict__ mult,
          float* __restrict__ out)
{
    const int w = threadIdx.x >> 6;     // wave 0..3
    const int L = threadIdx.x & 63;     // lane = local chunk
    const int b = blockIdx.x;
    const int c = threadIdx.x;          // global chunk id 0..255

    // 3200 floats = 12.8 KB: staging (4 waves x 192 float4 = 12288 B) overlaid
    // by the 128 x 25-float reduction slots (12800 B).
    __shared__ float shm[3200];
    __shared__ float sA[20], sM[16];    // sA[16..19] = trans[i*6+4] (init column)
    float4* stageW = ((float4*)shm) + w * 192;

    if (threadIdx.x < 16) {
        const int i = threadIdx.x >> 2, j = threadIdx.x & 3;
        sA[threadIdx.x] = trans[i * 6 + j];
        const float m0 = mult[j], m1 = mult[4 + j], m2 = mult[8 + j], m3 = mult[12 + j];
        const float mx = fmaxf(fmaxf(m0, m1), fmaxf(m2, m3));
        const float e0 = ex2((m0 - mx) * kLog2e), e1 = ex2((m1 - mx) * kLog2e);
        const float e2 = ex2((m2 - mx) * kLog2e), e3 = ex2((m3 - mx) * kLog2e);
        const float inv = rcpf(e0 + e1 + e2 + e3);
        const float ei = (i == 0) ? e0 : (i == 1) ? e1 : (i == 2) ? e2 : e3;
        sM[threadIdx.x] = (i == j) ? -1.0f : ei * inv;
        if (threadIdx.x < 4) sA[16 + threadIdx.x] = trans[threadIdx.x * 6 + 4];
    }
    __syncthreads();

    // wave-uniform constants -> SGPRs
    P1Params pp;
    #pragma unroll
    for (int i = 0; i < 4; ++i)
        #pragma unroll
        for (int j = 0; j < 4; ++j) {
            pp.AL[i][j] = rfl(trans[i * 6 + j] * kLog2e);
            pp.M[i][j]  = rfl(sM[i * 4 + j]);
        }
    #pragma unroll
    for (int j = 0; j < 4; ++j) {
        pp.wsv[j] = rfl(wsh[j]); pp.wwv[j] = rfl(wwo[j]); pp.wnv[j] = rfl(wno[j]);
    }
    pp.bwc = rfl(bwi[0]); pp.bnc = rfl(bno[0]);
    pp.sA = sA; pp.sM = sM;
    const float tcI0 = rfl(sA[16]), tcI1 = rfl(sA[17]);
    const float tcI2 = rfl(sA[18]), tcI3 = rfl(sA[19]);

    // wave's feats window: 64 chunks x 12 float4; chunk cl owns [12*cl, 12*cl+12)
    const float4* gF = (const float4*)feats + (size_t)b * 3072 + (size_t)w * 768;

    // per-lane staged-load base indices (stage s adds +3*s)
    int off[3];
    #pragma unroll
    for (int r = 0; r < 3; ++r) {
        const int S = r * 64 + L, cS = (S * 21846) >> 16;   // S/3, exact for S<192
        off[r] = cS * 12 + (S - cS * 3);
    }

    // ---- one-shot prologue loads: bias (8 regs) + packed tag chain (1 reg) ----
    float Bv[8];
    {
        const float4* bp = (const float4*)(bias + (size_t)b * TN + c * 8);
        const float4 b0 = bp[0], b1 = bp[1];
        Bv[0]=b0.x; Bv[1]=b0.y; Bv[2]=b0.z; Bv[3]=b0.w;
        Bv[4]=b1.x; Bv[5]=b1.y; Bv[6]=b1.z; Bv[7]=b1.w;
    }
    int packed;
    {
        const int4* tp = (const int4*)(tags + (size_t)b * TN + c * 8);
        const int4 ta = tp[0], tb = tp[1];
        int p0 = 0;
        if (c != 0) p0 = tags[(size_t)b * TN + c * 8 - 1];
        packed = p0 | (ta.x << 2) | (ta.y << 4) | (ta.z << 6) | (ta.w << 8)
               | (tb.x << 10) | (tb.y << 12) | (tb.z << 14) | (tb.w << 16);
    }

    float P[4][4], lacc[4] = {0.f, 0.f, 0.f, 0.f};
    #pragma unroll
    for (int i = 0; i < 4; ++i)
        #pragma unroll
        for (int j = 0; j < 4; ++j) P[i][j] = (i == j) ? 1.0f : 0.0f;
    float gold = 0.0f;
    const bool isC0 = (c == 0);

    // ---- prologue: issue feats stages 0..2 (depth-3 pipeline) ----
    float4 tF[4][3];
    #pragma unroll
    for (int s = 0; s < 3; ++s)
        #pragma unroll
        for (int r = 0; r < 3; ++r) tF[s][r] = gF[off[r] + s * 3];

    #pragma unroll
    for (int s = 0; s < 4; ++s) {
        // transpose stage s into wave-private LDS (vmcnt wait lands here)
        #pragma unroll
        for (int r = 0; r < 3; ++r) {
            const int S = r * 64 + L, cS = (S * 21846) >> 16, j = S - cS * 3;
            stageW[(j << 6) + ((cS + j) & 63)] = tF[s][r];
        }
        if (s == 0) {   // issue stage 3 (stays in flight across stages 0..2)
            #pragma unroll
            for (int r = 0; r < 3; ++r) tF[3][r] = gF[off[r] + 9];
        }
        const float4 fA = stageW[(0 << 6) + ( L      & 63)];
        const float4 fB = stageW[(1 << 6) + ((L + 1) & 63)];
        const float4 fC = stageW[(2 << 6) + ((L + 2) & 63)];
        {   // step t = 2s : floats 12s+0..3 ; tag fields at shift 4s
            const float fi0 = fA.x, fi1 = fA.y, fi2 = fA.z, fi3 = fA.w;
            const int sh  = 4 * s;
            const int idx = (packed >> sh) & 15;
            const int tg  = (packed >> (sh + 2)) & 3;
            const int pv  = (packed >> sh) & 3;
            if (isC0 && s == 0) {
                const float a0 = fi0 + tcI0, a1 = fi1 + tcI1;
                const float a2 = fi2 + tcI2, a3 = fi3 + tcI3;
                const float mx = fmaxf(fmaxf(a0, a1), fmaxf(a2, a3));
                const float e0 = ex2((a0 - mx) * kLog2e);
                const float e1 = ex2((a1 - mx) * kLog2e);
                const float e2 = ex2((a2 - mx) * kLog2e);
                const float e3 = ex2((a3 - mx) * kLog2e);
                #pragma unroll
                for (int j = 0; j < 4; ++j) {
                    P[0][j] = e0; P[1][j] = e1; P[2][j] = e2; P[3][j] = e3;
                    lacc[j] = mx * kLog2e;
                }
                gold = sel4(tcI0, tcI1, tcI2, tcI3, tg)
                     + sel4(fi0, fi1, fi2, fi3, tg);
            } else {
                step4(pp, fi0, fi1, fi2, fi3, Bv[2*s], idx, tg, pv,
                      false, P, lacc, gold);
            }
        }
        {   // step t = 2s+1 : floats 12s+6..9 ; tag fields at shift 4s+2
            const float fi0 = fB.z, fi1 = fB.w, fi2 = fC.x, fi3 = fC.y;
            const int sh  = 4 * s + 2;
            const int idx = (packed >> sh) & 15;
            const int tg  = (packed >> (sh + 2)) & 3;
            const int pv  = (packed >> sh) & 3;
            step4(pp, fi0, fi1, fi2, fi3, Bv[2*s+1], idx, tg, pv,
                  (s & 1) == 1, P, lacc, gold);
        }
    }

    // ---- tree level 0 in registers via shuffle (same binary topology) ----
    {
        float oP[4][4], os[4];
        #pragma unroll
        for (int i = 0; i < 4; ++i)
            #pragma unroll
            for (int j = 0; j < 4; ++j) oP[i][j] = __shfl_xor(P[i][j], 1, 64);
        #pragma unroll
        for (int j = 0; j < 4; ++j) os[j] = __shfl_xor(lacc[j], 1, 64);
        const float og = __shfl_xor(gold, 1, 64);
        // even lane: own = earlier (chunk c), partner = later (chunk c+1)
        float Ce[4][4], sc[4];
        compose4(oP, os, P, lacc, Ce, sc);
        #pragma unroll
        for (int i = 0; i < 4; ++i)
            #pragma unroll
            for (int j = 0; j < 4; ++j) P[i][j] = Ce[i][j];
        #pragma unroll
        for (int j = 0; j < 4; ++j) lacc[j] = sc[j];
        gold += og;                     // meaningful on even lanes only
    }

    // ---- write 128 pair-results; then 7 LDS levels ----
    __syncthreads();                    // all staging reads done; safe to overlay
    if ((c & 1) == 0) {
        float* my = shm + (size_t)(c >> 1) * 25;
        #pragma unroll
        for (int i = 0; i < 4; ++i)
            #pragma unroll
            for (int j = 0; j < 4; ++j) my[i * 4 + j] = P[i][j];
        #pragma unroll
        for (int j = 0; j < 4; ++j) my[16 + j] = lacc[j];
        my[20] = gold;
    }
    #pragma unroll 1
    for (int l = 0; l < 7; ++l) {
        __syncthreads();
        const int cnt = 64 >> l;
        if (threadIdx.x < cnt) {
            float* se = shm + (size_t)(threadIdx.x << (l + 1)) * 25;  // earlier
            const float* sl = se + (25 << l);                         // later
            float Be_[4][4], sb[4], Ae[4][4], sa[4];
            #pragma unroll
            for (int i = 0; i < 4; ++i)
                #pragma unroll
                for (int j = 0; j < 4; ++j) { Be_[i][j] = se[i*4+j]; Ae[i][j] = sl[i*4+j]; }
            #pragma unroll
            for (int j = 0; j < 4; ++j) { sb[j] = se[16+j]; sa[j] = sl[16+j]; }
            const float gsum = se[20] + sl[20];
            float Ce[4][4], sc[4];
            compose4(Ae, sa, Be_, sb, Ce, sc);     // later ∘ earlier
            #pragma unroll
            for (int i = 0; i < 4; ++i)
                #pragma unroll
                for (int j = 0; j < 4; ++j) se[i*4+j] = Ce[i][j];
            #pragma unroll
            for (int j = 0; j < 4; ++j) se[16+j] = sc[j];
            se[20] = gsum;
        }
    }

    if (threadIdx.x == 0) {             // slot 0 was written by this thread
        const float p00 = shm[0], p10 = shm[4], p20 = shm[8], p30 = shm[12];
        const float so0 = shm[16];
        const float gall = shm[20];
        const float t50 = trans[30], t51 = trans[31], t52 = trans[32], t53 = trans[33];
        const float ssum = p00 * ex2(t50 * kLog2e) + p10 * ex2(t51 * kLog2e)
                         + p20 * ex2(t52 * kLog2e) + p30 * ex2(t53 * kLog2e);
        const float fwd = (so0 + lg2(ssum)) * kLn2;
        const int lastT = tags[(size_t)b * TN + TN - 1];
        const float gfin = gall + sel4(t50, t51, t52, t53, lastT);
        out[b] = fwd - gfin;
    }
}

extern "C" void kernel_launch(void* const* d_in, const int* in_sizes, int n_in,
                              void* d_out, int out_size, void* d_ws, size_t ws_size,
                              hipStream_t stream)
{
    const float* feats = (const float*)d_in[0];
    const float* bias  = (const float*)d_in[1];
    const int*   tags  = (const int*)d_in[2];
    const float* trans = (const float*)d_in[3];
    const float* wsh   = (const float*)d_in[4];
    const float* bno   = (const float*)d_in[5];
    const float* bwi   = (const float*)d_in[6];
    const float* wwo   = (const float*)d_in[7];
    const float* wno   = (const float*)d_in[8];
    const float* mult  = (const float*)d_in[9];
    float* out = (float*)d_out;
    (void)d_ws; (void)ws_size;   // workspace not needed

    crf_fused<<<BN, 256, 0, stream>>>(
        feats, bias, tags, trans, wsh, bno, bwi, wwo, wno, mult, out);
}